// Round 5
// baseline (120.336 us; speedup 1.0000x reference)
//
#include <hip/hip_runtime.h>
#include <math.h>

#define C_NUM 80
#define T_NUM 256
#define EPSF  1e-7f

// ws layout: [0..3] counter (memset to 0 each call), [64..] 544 float4 partials
#define PBLK_OFF 64

__device__ __forceinline__ float softplusf(float z) {
    return fmaxf(z, 0.0f) + log1pf(expf(-fabsf(z)));
}

__device__ __forceinline__ void tile_decode(int tile, int& s, int& b, int& chunk,
                                            int& H, float& stride) {
    if (tile < 400)      { s = 0; b = tile / 25;             chunk = tile % 25; H = 80; stride =  8.f; }
    else if (tile < 512) { int r = tile - 400; s = 1; b = r / 7; chunk = r % 7; H = 40; stride = 16.f; }
    else                 { int r = tile - 512; s = 2; b = r / 2; chunk = r % 2; H = 20; stride = 32.f; }
}

// One block = one 256-anchor tile of one (scale, image). 544 blocks total.
// Class mapping: wave w owns classes [20w,20w+20); lane = (cq,ag): cq=lane>>4
// picks a 5-class strip, ag=lane&15 picks 4 anchors of subtile st (0..3).
// All 20 float4 loads are issued before the match phase so the HBM stream is
// in flight during decode/IoU/CIoU.
__global__ __launch_bounds__(256)
void yolo_fused(const float* __restrict__ cls0, const float* __restrict__ cls1,
                const float* __restrict__ cls2,
                const float* __restrict__ reg0, const float* __restrict__ reg1,
                const float* __restrict__ reg2,
                const float* __restrict__ tboxes, const int* __restrict__ t_batch,
                const int* __restrict__ t_cls,
                unsigned int* __restrict__ counter, float4* __restrict__ pblk,
                float* __restrict__ out)
{
    __shared__ float s_x1[T_NUM], s_y1[T_NUM], s_x2[T_NUM], s_y2[T_NUM], s_ar[T_NUM];
    __shared__ int   s_tc[T_NUM];
    __shared__ int   s_list[T_NUM];
    __shared__ int   s_wcnt[4];
    __shared__ float4 s_wmax[4][4][16];     // [wave][st][ag]: 20-class max of 4 anchors
    __shared__ int   s_btc[T_NUM] __attribute__((aligned(16)));
    __shared__ float s_red[4][4];
    __shared__ int   s_last;

    const int tid = threadIdx.x;
    const int bid = blockIdx.x;
    int s, b, chunk, H; float stride;
    tile_decode(bid, s, b, chunk, H, stride);
    const int A = H * H;
    const float* clsp = (s == 0) ? cls0 : (s == 1) ? cls1 : cls2;
    const float* regp = (s == 0) ? reg0 : (s == 1) ? reg1 : reg2;

    // ---- stage targets + order-preserving per-image compaction ----
    {
        float4 t4 = reinterpret_cast<const float4*>(tboxes)[tid];
        s_x1[tid] = t4.x; s_y1[tid] = t4.y; s_x2[tid] = t4.z; s_y2[tid] = t4.w;
        s_ar[tid] = (t4.z - t4.x) * (t4.w - t4.y);
        s_tc[tid] = t_cls[tid];
    }
    const int lane = tid & 63, wave = tid >> 6;
    int match = (t_batch[tid] == b) ? 1 : 0;
    unsigned long long mask = __ballot(match != 0);
    if (lane == 0) s_wcnt[wave] = __popcll(mask);
    __syncthreads();
    int base = 0;
    #pragma unroll
    for (int w = 0; w < 4; ++w) if (w < wave) base += s_wcnt[w];
    const int nT = s_wcnt[0] + s_wcnt[1] + s_wcnt[2] + s_wcnt[3];
    if (match) {
        int pfx = __popcll(mask & (((unsigned long long)1 << lane) - 1ull));
        s_list[base + pfx] = tid;       // ascending -> argmax first-max tie kept
    }
    __syncthreads();

    // ---- issue ALL class loads now (20 float4 per thread, kept live) ----
    const int cq = lane >> 4, ag = lane & 15;
    const int cbase = wave * 20 + cq * 5;
    float4 z[4][5];
    #pragma unroll
    for (int st = 0; st < 4; ++st) {
        int a0 = chunk * 256 + st * 64 + 4 * ag;
        const float* pst = clsp + ((size_t)(b * C_NUM + cbase)) * (size_t)A
                         + ((a0 < A) ? a0 : 0);
        #pragma unroll
        for (int k = 0; k < 5; ++k)
            z[st][k] = *reinterpret_cast<const float4*>(pst + (size_t)k * A);
    }

    // ---- match phase (overlaps the class stream) ----
    const int a = chunk * 256 + tid;
    float cnt = 0.f, boxs = 0.f;
    if (a < A) {
        const float* rp = regp + (b * 4) * A + a;
        float rx = rp[0], ry = rp[A], rw = rp[2 * A], rh = rp[3 * A];
        float gx = (float)(a % H), gy = (float)(a / H);
        float x = (1.f / (1.f + expf(-rx)) + gx) * stride;
        float y = (1.f / (1.f + expf(-ry)) + gy) * stride;
        float w = expf(rw) * stride;
        float h = expf(rh) * stride;
        float px1 = x - 0.5f * w, py1 = y - 0.5f * h;
        float px2 = x + 0.5f * w, py2 = y + 0.5f * h;
        float pw = px2 - px1, ph = py2 - py1;
        float parea = pw * ph;

        float maxiou = -1.f; int best = 0;
        for (int j = 0; j < nT; ++j) {
            int t = s_list[j];
            float ix = fminf(px2, s_x2[t]) - fmaxf(px1, s_x1[t]);
            float iy = fminf(py2, s_y2[t]) - fmaxf(py1, s_y1[t]);
            float inter = fmaxf(ix, 0.f) * fmaxf(iy, 0.f);
            float iou = inter / (parea + s_ar[t] - inter + EPSF);
            if (iou > maxiou) { maxiou = iou; best = t; }
        }
        const bool pos = maxiou > 0.5f;
        s_btc[tid] = pos ? s_tc[best] : -1;

        if (pos) {
            cnt = 1.f;
            float gx1 = s_x1[best], gy1 = s_y1[best], gx2 = s_x2[best], gy2 = s_y2[best];
            float gw = gx2 - gx1, gh = gy2 - gy1;
            float ix = fminf(px2, gx2) - fmaxf(px1, gx1);
            float iy = fminf(py2, gy2) - fmaxf(py1, gy1);
            float inter = fmaxf(ix, 0.f) * fmaxf(iy, 0.f);
            float uni = parea + gw * gh - inter + EPSF;
            float iou = inter / uni;
            float cw = fmaxf(px2, gx2) - fminf(px1, gx1);
            float ch = fmaxf(py2, gy2) - fminf(py1, gy1);
            float c2 = cw * cw + ch * ch + EPSF;
            float dx = 0.5f * ((px1 + px2) - (gx1 + gx2));
            float dy = 0.5f * ((py1 + py2) - (gy1 + gy2));
            float rho2 = dx * dx + dy * dy;
            float dv = atanf(gw / (gh + EPSF)) - atanf(pw / (ph + EPSF));
            float v = 0.40528473456935108577f * dv * dv;   // (4/pi^2) dv^2
            float alpha = v / (v - iou + 1.f + EPSF);
            boxs = 1.f - (iou - rho2 / c2 - alpha * v);
        }
    } else {
        s_btc[tid] = -1;
    }

    // ---- per-strip class max -> s_wmax ----
    #pragma unroll
    for (int st = 0; st < 4; ++st) {
        float4 mx;
        mx.x = fmaxf(fmaxf(fmaxf(z[st][0].x, z[st][1].x), fmaxf(z[st][2].x, z[st][3].x)), z[st][4].x);
        mx.y = fmaxf(fmaxf(fmaxf(z[st][0].y, z[st][1].y), fmaxf(z[st][2].y, z[st][3].y)), z[st][4].y);
        mx.z = fmaxf(fmaxf(fmaxf(z[st][0].z, z[st][1].z), fmaxf(z[st][2].z, z[st][3].z)), z[st][4].z);
        mx.w = fmaxf(fmaxf(fmaxf(z[st][0].w, z[st][1].w), fmaxf(z[st][2].w, z[st][3].w)), z[st][4].w);
        #pragma unroll
        for (int d = 16; d <= 32; d <<= 1) {
            mx.x = fmaxf(mx.x, __shfl_xor(mx.x, d, 64));
            mx.y = fmaxf(mx.y, __shfl_xor(mx.y, d, 64));
            mx.z = fmaxf(mx.z, __shfl_xor(mx.z, d, 64));
            mx.w = fmaxf(mx.w, __shfl_xor(mx.w, d, 64));
        }
        if (cq == 0) s_wmax[wave][st][ag] = mx;
    }
    __syncthreads();

    // ---- cls-BCE on the already-loaded registers (pos anchors only) ----
    float clss = 0.f;
    #pragma unroll
    for (int st = 0; st < 4; ++st) {
        int a0 = chunk * 256 + st * 64 + 4 * ag;
        if (a0 < A) {
            int4 t4 = *reinterpret_cast<const int4*>(&s_btc[st * 64 + 4 * ag]);
            if ((t4.x >= 0) | (t4.y >= 0) | (t4.z >= 0) | (t4.w >= 0)) {
                #pragma unroll
                for (int k = 0; k < 5; ++k) {
                    const int cg = cbase + k;
                    if (t4.x >= 0) { clss += softplusf(z[st][k].x); if (cg == t4.x) clss -= z[st][k].x; }
                    if (t4.y >= 0) { clss += softplusf(z[st][k].y); if (cg == t4.y) clss -= z[st][k].y; }
                    if (t4.z >= 0) { clss += softplusf(z[st][k].z); if (cg == t4.z) clss -= z[st][k].z; }
                    if (t4.w >= 0) { clss += softplusf(z[st][k].w); if (cg == t4.w) clss -= z[st][k].w; }
                }
            }
        }
    }

    // ---- obj for owner anchor `tid` ----
    float objs = 0.f;
    if (a < A) {
        const int st = tid >> 6, agx = (tid & 63) >> 2, comp = tid & 3;
        float m = -INFINITY;
        #pragma unroll
        for (int w = 0; w < 4; ++w)
            m = fmaxf(m, reinterpret_cast<const float*>(&s_wmax[w][st][agx])[comp]);
        bool pos = s_btc[tid] >= 0;
        objs = softplusf(m) - (pos ? m : 0.f);
    }

    // ---- block reduction {npos, box, cls, obj} ----
    #pragma unroll
    for (int off = 32; off > 0; off >>= 1) {
        cnt  += __shfl_down(cnt,  off, 64);
        boxs += __shfl_down(boxs, off, 64);
        clss += __shfl_down(clss, off, 64);
        objs += __shfl_down(objs, off, 64);
    }
    if (lane == 0) {
        s_red[wave][0] = cnt;  s_red[wave][1] = boxs;
        s_red[wave][2] = clss; s_red[wave][3] = objs;
    }
    __syncthreads();
    if (tid == 0) {
        float4 v;
        v.x = s_red[0][0] + s_red[1][0] + s_red[2][0] + s_red[3][0];
        v.y = s_red[0][1] + s_red[1][1] + s_red[2][1] + s_red[3][1];
        v.z = s_red[0][2] + s_red[1][2] + s_red[2][2] + s_red[3][2];
        v.w = s_red[0][3] + s_red[1][3] + s_red[2][3] + s_red[3][3];
        pblk[bid] = v;
        __threadfence();                              // release partials device-wide
        unsigned int old = atomicAdd(counter, 1u);    // device-scope
        s_last = (old == 543u) ? 1 : 0;
    }
    __syncthreads();

    // ---- last finishing block folds all partials and writes the scalar ----
    if (s_last) {
        __threadfence();                              // acquire
        if (tid < 64) {
            float np0 = 0.f, np1 = 0.f, np2 = 0.f, bx0 = 0.f, bx1 = 0.f, bx2 = 0.f;
            float cl0 = 0.f, cl1 = 0.f, cl2 = 0.f, ob0 = 0.f, ob1 = 0.f, ob2 = 0.f;
            for (int i = tid; i < 544; i += 64) {
                float4 v = pblk[i];
                if (i < 400)      { np0 += v.x; bx0 += v.y; cl0 += v.z; ob0 += v.w; }
                else if (i < 512) { np1 += v.x; bx1 += v.y; cl1 += v.z; ob1 += v.w; }
                else              { np2 += v.x; bx2 += v.y; cl2 += v.z; ob2 += v.w; }
            }
            #pragma unroll
            for (int off = 32; off > 0; off >>= 1) {
                np0 += __shfl_down(np0, off, 64); np1 += __shfl_down(np1, off, 64);
                np2 += __shfl_down(np2, off, 64); bx0 += __shfl_down(bx0, off, 64);
                bx1 += __shfl_down(bx1, off, 64); bx2 += __shfl_down(bx2, off, 64);
                cl0 += __shfl_down(cl0, off, 64); cl1 += __shfl_down(cl1, off, 64);
                cl2 += __shfl_down(cl2, off, 64); ob0 += __shfl_down(ob0, off, 64);
                ob1 += __shfl_down(ob1, off, 64); ob2 += __shfl_down(ob2, off, 64);
            }
            if (tid == 0) {
                float np[3] = { fmaxf(np0, 1.f), fmaxf(np1, 1.f), fmaxf(np2, 1.f) };
                float bx[3] = { bx0, bx1, bx2 };
                float cl[3] = { cl0, cl1, cl2 };
                float ob[3] = { ob0, ob1, ob2 };
                const float inv_anch[3] = { 1.f / (16.f * 6400.f), 1.f / (16.f * 1600.f), 1.f / (16.f * 400.f) };
                float total = 0.f;
                #pragma unroll
                for (int k = 0; k < 3; ++k)
                    total += 7.5f * bx[k] / np[k]
                           + 0.5f * cl[k] / (np[k] * (float)C_NUM)
                           + ob[k] * inv_anch[k];
                out[0] = total;
            }
        }
    }
}

extern "C" void kernel_launch(void* const* d_in, const int* in_sizes, int n_in,
                              void* d_out, int out_size, void* d_ws, size_t ws_size,
                              hipStream_t stream) {
    const float *cls[3] = {nullptr, nullptr, nullptr};
    const float *reg[3] = {nullptr, nullptr, nullptr};
    const float *tboxes = nullptr;
    const int *t_batch = nullptr, *t_cls = nullptr;
    for (int i = 0; i < n_in; ++i) {
        switch (in_sizes[i]) {
            case 16 * 80 * 6400: cls[0] = (const float*)d_in[i]; break;
            case 16 * 80 * 1600: cls[1] = (const float*)d_in[i]; break;
            case 16 * 80 * 400:  cls[2] = (const float*)d_in[i]; break;
            case 16 * 4 * 6400:  reg[0] = (const float*)d_in[i]; break;
            case 16 * 4 * 1600:  reg[1] = (const float*)d_in[i]; break;
            case 16 * 4 * 400:   reg[2] = (const float*)d_in[i]; break;
            case 256 * 4:        tboxes = (const float*)d_in[i]; break;
            case 256:
                if (!t_batch) t_batch = (const int*)d_in[i];
                else          t_cls   = (const int*)d_in[i];
                break;
            default: break;
        }
    }
    unsigned int* counter = (unsigned int*)d_ws;
    float4*       pblk    = (float4*)((char*)d_ws + PBLK_OFF);
    float*        out     = (float*)d_out;

    hipMemsetAsync(counter, 0, sizeof(unsigned int), stream);
    hipLaunchKernelGGL(yolo_fused, dim3(544), dim3(256), 0, stream,
                       cls[0], cls[1], cls[2], reg[0], reg[1], reg[2],
                       tboxes, t_batch, t_cls, counter, pblk, out);
}